// Round 1
// baseline (1478.701 us; speedup 1.0000x reference)
//
#include <hip/hip_runtime.h>
#include <cstdint>
#include <cstddef>

typedef unsigned short u16;
typedef __attribute__((ext_vector_type(8))) short short8;
typedef __attribute__((ext_vector_type(4))) float f32x4;

// ---------- helpers ----------
__device__ __forceinline__ u16 f2b(float f) {
  union { float f; uint32_t u; } v; v.f = f;
  uint32_t u = v.u;
  uint32_t r = (u + 0x7FFFu + ((u >> 16) & 1u)) >> 16;
  return (u16)r;
}

__device__ __forceinline__ void gload_lds16(const u16* g, u16* l) {
  __builtin_amdgcn_global_load_lds(
      (const __attribute__((address_space(1))) void*)g,
      (__attribute__((address_space(3))) void*)l, 16, 0, 0);
}

// ---------- prep kernels ----------
__global__ void prep_adj(const float* __restrict__ logits, const int* __restrict__ topo,
                         float* __restrict__ adj_out, int* __restrict__ parlist,
                         int* __restrict__ ecnt, float* __restrict__ rcnt,
                         const float* __restrict__ mu_b, const float* __restrict__ lv_b,
                         float* __restrict__ mbias) {
  __shared__ int pos[128];
  int i = threadIdx.x;                 // node id, block of 128
  pos[topo[i]] = i;
  __syncthreads();
  int mypos = pos[i];
  int c_all = 0, c_eff = 0;
  for (int j = 0; j < 128; ++j) {
    float v = (i != j && logits[i * 128 + j] > 0.0f) ? 1.0f : 0.0f;
    adj_out[i * 128 + j] = v;
    if (v != 0.0f) {
      c_all++;
      if (pos[j] < mypos) parlist[i * 128 + c_eff++] = j;  // only earlier-in-order parents
    }
  }
  ecnt[i] = c_eff;
  rcnt[i] = 1.0f / fmaxf((float)c_all, 1.0f);              // denominator uses FULL count
  mbias[i] = (i < 64) ? mu_b[i] : lv_b[i - 64];
}

__global__ void prep_semT(const float* __restrict__ W1, const float* __restrict__ W2,
                          float* __restrict__ W1T, float* __restrict__ W2T) {
  int node = blockIdx.x, t = threadIdx.x;
  const float* w1 = W1 + node * 4096; float* o1 = W1T + node * 4096;
  for (int e = t; e < 4096; e += 256) { int j = e >> 7, k = e & 127; o1[k * 32 + j] = w1[e]; }
  const float* w2 = W2 + node * 2048; float* o2 = W2T + node * 2048;
  for (int e = t; e < 2048; e += 256) { int l = e >> 5, jj = e & 31; o2[jj * 64 + l] = w2[e]; }
}

__global__ __launch_bounds__(256)
void cvt_weights(const float* __restrict__ e1, const float* __restrict__ e2,
                 const float* __restrict__ muw, const float* __restrict__ lvw,
                 const float* __restrict__ d1, const float* __restrict__ d2,
                 const float* __restrict__ d3, u16* __restrict__ dst) {
  int i = blockIdx.x * 256 + threadIdx.x;
  int stride = gridDim.x * 256;
  for (; i < 1359872; i += stride) {
    float v;
    if      (i < 524288) v = e1[i];
    else if (i < 655360) v = e2[i - 524288];
    else if (i < 671744) v = muw[i - 655360];
    else if (i < 688128) v = lvw[i - 671744];
    else if (i < 704512) v = d1[i - 688128];
    else if (i < 835584) v = d2[i - 704512];
    else                 v = d3[i - 835584];
    dst[i] = f2b(v);
  }
}

__global__ __launch_bounds__(256)
void cvt_f32_bf16(const float* __restrict__ src, u16* __restrict__ dst, size_t n4) {
  size_t i = (size_t)blockIdx.x * blockDim.x + threadIdx.x;
  size_t stride = (size_t)gridDim.x * blockDim.x;
  for (; i < n4; i += stride) {
    float4 v = ((const float4*)src)[i];
    ushort4 o;
    o.x = f2b(v.x); o.y = f2b(v.y); o.z = f2b(v.z); o.w = f2b(v.w);
    ((ushort4*)dst)[i] = o;
  }
}

// ---------- bf16 MFMA GEMM: C = act(A @ W^T + bias) ----------
// A: (M,K) row-major bf16.  W: (Ncols,K) row-major bf16 (i.e. B^T input).
// 128x128 tile, BK=64, 4 waves (2x2 of 64x64), 16x16x32 bf16 MFMA.
template <int OUT_BF16, int RELU>
__global__ __launch_bounds__(256)
void gemm_bt(const u16* __restrict__ A, const u16* __restrict__ W,
             const float* __restrict__ bias, void* __restrict__ Cout,
             int M, int Ncols, int K) {
  __shared__ __align__(16) u16 As[128 * 64];
  __shared__ __align__(16) u16 Bs[128 * 64];
  const int tid = threadIdx.x;
  const int tile_n = blockIdx.x, tile_m = blockIdx.y;
  const int wid = tid >> 6, lane = tid & 63;
  const int wm = (wid >> 1) * 64, wn = (wid & 1) * 64;
  const int lr = lane & 15, lg = lane >> 4;
  f32x4 acc[4][4] = {};
  const size_t arow0 = (size_t)tile_m * 128;
  const size_t brow0 = (size_t)tile_n * 128;

  for (int kt = 0; kt < K; kt += 64) {
#pragma unroll
    for (int is = 0; is < 4; ++is) {
      int e = is * 2048 + tid * 8;   // element index in 128x64 tile
      int r = e >> 6, c = e & 63;
      gload_lds16(A + (arow0 + r) * K + kt + c, &As[e]);
      gload_lds16(W + (brow0 + r) * K + kt + c, &Bs[e]);
    }
    __syncthreads();
#pragma unroll
    for (int kk = 0; kk < 64; kk += 32) {
      short8 av[4], bv[4];
#pragma unroll
      for (int m = 0; m < 4; ++m)
        av[m] = *(const short8*)&As[(wm + m * 16 + lr) * 64 + kk + lg * 8];
#pragma unroll
      for (int n = 0; n < 4; ++n)
        bv[n] = *(const short8*)&Bs[(wn + n * 16 + lr) * 64 + kk + lg * 8];
#pragma unroll
      for (int m = 0; m < 4; ++m)
#pragma unroll
        for (int n = 0; n < 4; ++n)
          acc[m][n] = __builtin_amdgcn_mfma_f32_16x16x32_bf16(av[m], bv[n], acc[m][n], 0, 0, 0);
    }
    __syncthreads();
  }
  // epilogue: C/D layout col = lane&15, row = (lane>>4)*4 + reg  [m89-verified]
#pragma unroll
  for (int n = 0; n < 4; ++n) {
    int col = (int)brow0 + wn + n * 16 + lr;
    float bval = bias[col];
#pragma unroll
    for (int m = 0; m < 4; ++m) {
#pragma unroll
      for (int r = 0; r < 4; ++r) {
        int row = (int)arow0 + wm + m * 16 + lg * 4 + r;
        float v = acc[m][n][r] + bval;
        if (RELU) v = fmaxf(v, 0.0f);
        if (OUT_BF16) ((u16*)Cout)[(size_t)row * Ncols + col] = f2b(v);
        else          ((float*)Cout)[(size_t)row * Ncols + col] = v;
      }
    }
  }
}

// ---------- reparameterize + KL partials ----------
__global__ __launch_bounds__(256)
void reparam_kernel(const float* __restrict__ mulv, const float* __restrict__ eps,
                    float* __restrict__ mu_out, float* __restrict__ lv_out,
                    float* __restrict__ z, float* __restrict__ klpart) {
  int gid = blockIdx.x * 256 + threadIdx.x;   // over B*N*L = 2,097,152
  int row = gid >> 6, l = gid & 63;
  float mu = mulv[(size_t)row * 128 + l];
  float lv = mulv[(size_t)row * 128 + 64 + l];
  mu_out[gid] = mu;
  lv_out[gid] = lv;
  float e = eps[gid];
  z[gid] = mu + e * expf(0.5f * lv);
  float kt = 1.0f + lv - mu * mu - expf(lv);
  for (int o = 32; o > 0; o >>= 1) kt += __shfl_down(kt, o);
  __shared__ float red[4];
  int lane = threadIdx.x & 63, w = threadIdx.x >> 6;
  if (lane == 0) red[w] = kt;
  __syncthreads();
  if (threadIdx.x == 0) klpart[blockIdx.x] = red[0] + red[1] + red[2] + red[3];
}

__global__ void kl_final(const float* __restrict__ klpart, float* __restrict__ out) {
  __shared__ float red[256];
  float s = 0.0f;
  for (int i = threadIdx.x; i < 8192; i += 256) s += klpart[i];
  red[threadIdx.x] = s;
  __syncthreads();
  for (int st = 128; st > 0; st >>= 1) {
    if (threadIdx.x < st) red[threadIdx.x] += red[threadIdx.x + st];
    __syncthreads();
  }
  if (threadIdx.x == 0) out[0] = -0.5f * red[0];
}

// ---------- SEM sequential scan: one block per batch element ----------
__global__ __launch_bounds__(64)
void sem_scan(const float* __restrict__ z, u16* __restrict__ ztb,
              const float* __restrict__ W1T, const float* __restrict__ W2T,
              const float* __restrict__ b1, const float* __restrict__ b2,
              const int* __restrict__ parlist, const int* __restrict__ ecnt,
              const float* __restrict__ rcnt, const int* __restrict__ topo) {
  int b = blockIdx.x, lane = threadIdx.x;
  __shared__ float tz[128 * 64];   // 32 KB, full per-batch state in f32
  __shared__ float feat[128];
  __shared__ float hhs[32];
  for (int i = lane; i < 8192; i += 64) tz[i] = 0.0f;
  __syncthreads();
  for (int s = 0; s < 128; ++s) {
    int node = topo[s];
    int pc = ecnt[node];
    const int* pl = parlist + node * 128;
    float agg = 0.0f;
    for (int i = 0; i < pc; ++i) agg += tz[pl[i] * 64 + lane];
    agg *= rcnt[node];
    feat[lane] = z[((size_t)b * 128 + node) * 64 + lane];
    feat[64 + lane] = agg;
    __syncthreads();
    // hh = relu(feat @ W1[node]^T + b1): lane j computes half-k of output j&31
    int j = lane & 31, half = lane >> 5;
    const float* w1 = W1T + node * 4096 + half * 2048;   // W1T[node][k][j]
    float a = 0.0f;
#pragma unroll 8
    for (int kk = 0; kk < 64; ++kk) a += feat[half * 64 + kk] * w1[kk * 32 + j];
    a += __shfl_xor(a, 32);
    float hh = fmaxf(a + b1[node * 32 + j], 0.0f);
    if (lane < 32) hhs[lane] = hh;
    __syncthreads();
    // out = hh @ W2[node]^T + b2: lane computes out[lane]
    const float* w2 = W2T + node * 2048;                 // W2T[node][j][l]
    float o = b2[node * 64 + lane];
#pragma unroll 8
    for (int jj = 0; jj < 32; ++jj) o += hhs[jj] * w2[jj * 64 + lane];
    tz[node * 64 + lane] = o;
    ztb[((size_t)b * 128 + node) * 64 + lane] = f2b(o);
    __syncthreads();
  }
}

// ---------- launch ----------
extern "C" void kernel_launch(void* const* d_in, const int* in_sizes, int n_in,
                              void* d_out, int out_size, void* d_ws, size_t ws_size,
                              hipStream_t stream) {
  const float* x          = (const float*)d_in[0];
  const float* eps        = (const float*)d_in[1];
  const float* adj_logits = (const float*)d_in[2];
  const float* enc_W1     = (const float*)d_in[3];
  const float* enc_b1     = (const float*)d_in[4];
  const float* enc_W2     = (const float*)d_in[5];
  const float* enc_b2     = (const float*)d_in[6];
  const float* mu_W       = (const float*)d_in[7];
  const float* mu_b       = (const float*)d_in[8];
  const float* lv_W       = (const float*)d_in[9];
  const float* lv_b       = (const float*)d_in[10];
  const float* dec_W1     = (const float*)d_in[11];
  const float* dec_b1     = (const float*)d_in[12];
  const float* dec_W2     = (const float*)d_in[13];
  const float* dec_b2     = (const float*)d_in[14];
  const float* dec_W3     = (const float*)d_in[15];
  const float* dec_b3     = (const float*)d_in[16];
  const float* sem_W1     = (const float*)d_in[17];
  const float* sem_b1     = (const float*)d_in[18];
  const float* sem_W2     = (const float*)d_in[19];
  const float* sem_b2     = (const float*)d_in[20];
  const int*   topo       = (const int*)d_in[21];

  float* out      = (float*)d_out;
  float* out_recon = out;
  float* out_mu    = out + 33554432;
  float* out_lv    = out + 35651584;
  float* out_adj   = out + 37748736;
  float* out_kl    = out + 37765120;

  char* ws = (char*)d_ws;
  u16*   xb      = (u16*)(ws + 0);              // 67,108,864 B (x bf16)
  u16*   d2b     = (u16*)(ws + 0);              // alias: d2 after xb is dead
  u16*   h1b     = (u16*)(ws + 67108864);       // 33,554,432 B
  u16*   d1b     = h1b;                          // alias: d1 after h1 is dead
  u16*   h2b     = (u16*)(ws + 100663296);      // 16,777,216 B
  float* mulv    = (float*)(ws + 117440512);    // 16,777,216 B
  float* zbuf    = (float*)(ws + 134217728);    //  8,388,608 B
  u16*   ztb     = (u16*)(ws + 142606336);      //  4,194,304 B
  u16*   wb      = (u16*)(ws + 146800640);      //  2,719,744 B
  float* W1T     = (float*)(ws + 149520384);    //  2,097,152 B
  float* W2T     = (float*)(ws + 151617536);    //  1,048,576 B
  int*   parlist = (int*)(ws + 152666112);      //     65,536 B
  int*   ecnt    = (int*)(ws + 152731648);
  float* rcnt    = (float*)(ws + 152732160);
  float* mbias   = (float*)(ws + 152732672);
  float* klp     = (float*)(ws + 152733184);    //     32,768 B

  u16* wE1 = wb;             // (512,1024)
  u16* wE2 = wb + 524288;    // (256,512)
  u16* wML = wb + 655360;    // (128,256) = mu_W rows ++ lv_W rows
  u16* wD1 = wb + 688128;    // (256,64)
  u16* wD2 = wb + 704512;    // (512,256)
  u16* wD3 = wb + 835584;    // (1024,512)

  prep_adj<<<1, 128, 0, stream>>>(adj_logits, topo, out_adj, parlist, ecnt, rcnt, mu_b, lv_b, mbias);
  prep_semT<<<128, 256, 0, stream>>>(sem_W1, sem_W2, W1T, W2T);
  cvt_weights<<<512, 256, 0, stream>>>(enc_W1, enc_W2, mu_W, lv_W, dec_W1, dec_W2, dec_W3, wb);
  cvt_f32_bf16<<<4096, 256, 0, stream>>>(x, xb, 8388608);

  dim3 blk(256);
  gemm_bt<1, 1><<<dim3(4, 256), blk, 0, stream>>>(xb,  wE1, enc_b1, h1b,  32768, 512, 1024);
  gemm_bt<1, 1><<<dim3(2, 256), blk, 0, stream>>>(h1b, wE2, enc_b2, h2b,  32768, 256, 512);
  gemm_bt<0, 0><<<dim3(1, 256), blk, 0, stream>>>(h2b, wML, mbias,  mulv, 32768, 128, 256);

  reparam_kernel<<<8192, 256, 0, stream>>>(mulv, eps, out_mu, out_lv, zbuf, klp);
  kl_final<<<1, 256, 0, stream>>>(klp, out_kl);

  sem_scan<<<256, 64, 0, stream>>>(zbuf, ztb, W1T, W2T, sem_b1, sem_b2, parlist, ecnt, rcnt, topo);

  gemm_bt<1, 1><<<dim3(2, 256), blk, 0, stream>>>(ztb, wD1, dec_b1, d1b,      32768, 256, 64);
  gemm_bt<1, 1><<<dim3(4, 256), blk, 0, stream>>>(d1b, wD2, dec_b2, d2b,      32768, 512, 256);
  gemm_bt<0, 0><<<dim3(8, 256), blk, 0, stream>>>(d2b, wD3, dec_b3, out_recon, 32768, 1024, 512);
}

// Round 3
// 798.958 us; speedup vs baseline: 1.8508x; 1.8508x over previous
//
#include <hip/hip_runtime.h>
#include <cstdint>
#include <cstddef>

typedef unsigned short u16;
typedef __attribute__((ext_vector_type(8))) short short8;
typedef __attribute__((ext_vector_type(4))) float f32x4;

// ---------- helpers ----------
__device__ __forceinline__ u16 f2b(float f) {
  union { float f; uint32_t u; } v; v.f = f;
  uint32_t u = v.u;
  uint32_t r = (u + 0x7FFFu + ((u >> 16) & 1u)) >> 16;
  return (u16)r;
}

__device__ __forceinline__ uint32_t pack2(float a, float b) {
  return (uint32_t)f2b(a) | ((uint32_t)f2b(b) << 16);
}

__device__ __forceinline__ void gload_lds16(const void* g, void* l) {
  __builtin_amdgcn_global_load_lds(
      (const __attribute__((address_space(1))) void*)g,
      (__attribute__((address_space(3))) void*)l, 16, 0, 0);
}
__device__ __forceinline__ void gload_lds4(const void* g, void* l) {
  __builtin_amdgcn_global_load_lds(
      (const __attribute__((address_space(1))) void*)g,
      (__attribute__((address_space(3))) void*)l, 4, 0, 0);
}

// ---------- prep kernels ----------
__global__ void prep_adj(const float* __restrict__ logits, const int* __restrict__ topo,
                         float* __restrict__ adj_out, int* __restrict__ parlist,
                         int* __restrict__ ecnt, float* __restrict__ rcnt,
                         const float* __restrict__ mu_b, const float* __restrict__ lv_b,
                         float* __restrict__ mbias) {
  __shared__ int pos[128];
  int i = threadIdx.x;                 // node id, block of 128
  pos[topo[i]] = i;
  __syncthreads();
  int mypos = pos[i];
  int c_all = 0, c_eff = 0;
  for (int j = 0; j < 128; ++j) {
    float v = (i != j && logits[i * 128 + j] > 0.0f) ? 1.0f : 0.0f;
    adj_out[i * 128 + j] = v;
    if (v != 0.0f) {
      c_all++;
      if (pos[j] < mypos) parlist[i * 128 + c_eff++] = j;  // only earlier-in-order parents
    }
  }
  while (c_eff & 15) parlist[i * 128 + c_eff++] = 128;     // pad to x16 with zero-row idx
  ecnt[i] = c_eff;                                          // padded count
  rcnt[i] = 1.0f / fmaxf((float)c_all, 1.0f);              // denominator uses FULL count
  mbias[i] = (i < 64) ? mu_b[i] : lv_b[i - 64];
}

// pack SEM weights as bf16 k-pairs (u32), transposed for lane-coalesced LDS reads
__global__ void prep_semP(const float* __restrict__ W1, const float* __restrict__ W2,
                          uint32_t* __restrict__ W1P, uint32_t* __restrict__ W2P) {
  int node = blockIdx.x, t = threadIdx.x;     // 256 threads
  const float* w1 = W1 + node * 4096;          // (32 j, 128 k)
  uint32_t* o1 = W1P + node * 2048;            // [kk2][j]
  for (int e = t; e < 2048; e += 256) {
    int kk2 = e >> 5, j = e & 31;
    o1[e] = pack2(w1[j * 128 + 2 * kk2], w1[j * 128 + 2 * kk2 + 1]);
  }
  const float* w2 = W2 + node * 2048;          // (64 l, 32 jj)
  uint32_t* o2 = W2P + node * 1024;            // [jj2][l]
  for (int e = t; e < 1024; e += 256) {
    int jj2 = e >> 6, l = e & 63;
    o2[e] = pack2(w2[l * 32 + 2 * jj2], w2[l * 32 + 2 * jj2 + 1]);
  }
}

__global__ __launch_bounds__(256)
void cvt_weights(const float* __restrict__ e1, const float* __restrict__ e2,
                 const float* __restrict__ muw, const float* __restrict__ lvw,
                 const float* __restrict__ d1, const float* __restrict__ d2,
                 const float* __restrict__ d3, u16* __restrict__ dst) {
  int i = blockIdx.x * 256 + threadIdx.x;
  int stride = gridDim.x * 256;
  for (; i < 1359872; i += stride) {
    float v;
    if      (i < 524288) v = e1[i];
    else if (i < 655360) v = e2[i - 524288];
    else if (i < 671744) v = muw[i - 655360];
    else if (i < 688128) v = lvw[i - 671744];
    else if (i < 704512) v = d1[i - 688128];
    else if (i < 835584) v = d2[i - 704512];
    else                 v = d3[i - 835584];
    dst[i] = f2b(v);
  }
}

__global__ __launch_bounds__(256)
void cvt_f32_bf16(const float* __restrict__ src, u16* __restrict__ dst, size_t n4) {
  size_t i = (size_t)blockIdx.x * blockDim.x + threadIdx.x;
  size_t stride = (size_t)gridDim.x * blockDim.x;
  for (; i < n4; i += stride) {
    float4 v = ((const float4*)src)[i];
    ushort4 o;
    o.x = f2b(v.x); o.y = f2b(v.y); o.z = f2b(v.z); o.w = f2b(v.w);
    ((ushort4*)dst)[i] = o;
  }
}

// ---------- bf16 MFMA GEMM: C = act(A @ W^T + bias) ----------
template <int OUT_BF16, int RELU>
__global__ __launch_bounds__(256)
void gemm_bt(const u16* __restrict__ A, const u16* __restrict__ W,
             const float* __restrict__ bias, void* __restrict__ Cout,
             int M, int Ncols, int K) {
  __shared__ __align__(16) u16 As[128 * 64];
  __shared__ __align__(16) u16 Bs[128 * 64];
  const int tid = threadIdx.x;
  const int tile_n = blockIdx.x, tile_m = blockIdx.y;
  const int wid = tid >> 6, lane = tid & 63;
  const int wm = (wid >> 1) * 64, wn = (wid & 1) * 64;
  const int lr = lane & 15, lg = lane >> 4;
  f32x4 acc[4][4] = {};
  const size_t arow0 = (size_t)tile_m * 128;
  const size_t brow0 = (size_t)tile_n * 128;

  for (int kt = 0; kt < K; kt += 64) {
#pragma unroll
    for (int is = 0; is < 4; ++is) {
      int e = is * 2048 + tid * 8;   // element index in 128x64 tile
      int r = e >> 6, c = e & 63;
      gload_lds16(A + (arow0 + r) * K + kt + c, &As[e]);
      gload_lds16(W + (brow0 + r) * K + kt + c, &Bs[e]);
    }
    __syncthreads();
#pragma unroll
    for (int kk = 0; kk < 64; kk += 32) {
      short8 av[4], bv[4];
#pragma unroll
      for (int m = 0; m < 4; ++m)
        av[m] = *(const short8*)&As[(wm + m * 16 + lr) * 64 + kk + lg * 8];
#pragma unroll
      for (int n = 0; n < 4; ++n)
        bv[n] = *(const short8*)&Bs[(wn + n * 16 + lr) * 64 + kk + lg * 8];
#pragma unroll
      for (int m = 0; m < 4; ++m)
#pragma unroll
        for (int n = 0; n < 4; ++n)
          acc[m][n] = __builtin_amdgcn_mfma_f32_16x16x32_bf16(av[m], bv[n], acc[m][n], 0, 0, 0);
    }
    __syncthreads();
  }
#pragma unroll
  for (int n = 0; n < 4; ++n) {
    int col = (int)brow0 + wn + n * 16 + lr;
    float bval = bias[col];
#pragma unroll
    for (int m = 0; m < 4; ++m) {
#pragma unroll
      for (int r = 0; r < 4; ++r) {
        int row = (int)arow0 + wm + m * 16 + lg * 4 + r;
        float v = acc[m][n][r] + bval;
        if (RELU) v = fmaxf(v, 0.0f);
        if (OUT_BF16) ((u16*)Cout)[(size_t)row * Ncols + col] = f2b(v);
        else          ((float*)Cout)[(size_t)row * Ncols + col] = v;
      }
    }
  }
}

// ---------- reparameterize + KL partials ----------
__global__ __launch_bounds__(256)
void reparam_kernel(const float* __restrict__ mulv, const float* __restrict__ eps,
                    float* __restrict__ mu_out, float* __restrict__ lv_out,
                    float* __restrict__ z, float* __restrict__ klpart) {
  int gid = blockIdx.x * 256 + threadIdx.x;   // over B*N*L = 2,097,152
  int row = gid >> 6, l = gid & 63;
  float mu = mulv[(size_t)row * 128 + l];
  float lv = mulv[(size_t)row * 128 + 64 + l];
  mu_out[gid] = mu;
  lv_out[gid] = lv;
  float e = eps[gid];
  z[gid] = mu + e * expf(0.5f * lv);
  float kt = 1.0f + lv - mu * mu - expf(lv);
  for (int o = 32; o > 0; o >>= 1) kt += __shfl_down(kt, o);
  __shared__ float red[4];
  int lane = threadIdx.x & 63, w = threadIdx.x >> 6;
  if (lane == 0) red[w] = kt;
  __syncthreads();
  if (threadIdx.x == 0) klpart[blockIdx.x] = red[0] + red[1] + red[2] + red[3];
}

__global__ void kl_final(const float* __restrict__ klpart, float* __restrict__ out) {
  __shared__ float red[256];
  float s = 0.0f;
  for (int i = threadIdx.x; i < 8192; i += 256) s += klpart[i];
  red[threadIdx.x] = s;
  __syncthreads();
  for (int st = 128; st > 0; st >>= 1) {
    if (threadIdx.x < st) red[threadIdx.x] += red[threadIdx.x + st];
    __syncthreads();
  }
  if (threadIdx.x == 0) out[0] = -0.5f * red[0];
}

// ---------- SEM sequential scan: one block (1 wave) per batch element ----------
// All per-step state in LDS; next node's weights/parlist prefetched one step
// ahead via global_load_lds (latency hidden under current step's ~1.5K cycles).
__device__ __forceinline__ void pref_node(int lane, int nd, int bufidx,
    const uint32_t* __restrict__ W1Pg, const uint32_t* __restrict__ W2Pg,
    const int* __restrict__ parlist,
    uint32_t (*w1buf)[2048], uint32_t (*w2buf)[1024], int (*plbuf)[128]) {
#pragma unroll
  for (int q = 0; q < 8; ++q)
    gload_lds16(W1Pg + (size_t)nd * 2048 + q * 256 + lane * 4,
                &w1buf[bufidx][q * 256 + lane * 4]);
#pragma unroll
  for (int q = 0; q < 4; ++q)
    gload_lds16(W2Pg + (size_t)nd * 1024 + q * 256 + lane * 4,
                &w2buf[bufidx][q * 256 + lane * 4]);
#pragma unroll
  for (int q = 0; q < 2; ++q)
    gload_lds4(parlist + nd * 128 + q * 64 + lane,
               &plbuf[bufidx][q * 64 + lane]);
}

__global__ __launch_bounds__(64)
void sem_scan(const float* __restrict__ z, u16* __restrict__ ztb,
              const uint32_t* __restrict__ W1Pg, const uint32_t* __restrict__ W2Pg,
              const float* __restrict__ b1, const float* __restrict__ b2,
              const int* __restrict__ parlist, const int* __restrict__ ecnt,
              const float* __restrict__ rcnt, const int* __restrict__ topo) {
  const int b = blockIdx.x, lane = threadIdx.x;
  __shared__ __align__(16) float tz[129 * 64];       // row 128 = zeros (pad target)
  __shared__ __align__(16) uint32_t w1buf[2][2048];  // bf16-pair [kk2][j], dbuf
  __shared__ __align__(16) uint32_t w2buf[2][1024];  // bf16-pair [jj2][l], dbuf
  __shared__ __align__(16) int plbuf[2][128];
  __shared__ __align__(16) float feat[128];
  __shared__ __align__(16) float hhs[32];
  __shared__ int topoS[128];
  __shared__ int ecS[128];
  __shared__ float rcS[128];

  for (int i = lane; i < 129 * 64; i += 64) tz[i] = 0.0f;
  for (int i = lane; i < 128; i += 64) {
    topoS[i] = topo[i]; ecS[i] = ecnt[i]; rcS[i] = rcnt[i];
  }
  __syncthreads();

  pref_node(lane, topoS[0], 0, W1Pg, W2Pg, parlist, w1buf, w2buf, plbuf);

  for (int s = 0; s < 128; ++s) {
    const int cur = s & 1;
    const int node = topoS[s];
    asm volatile("s_waitcnt vmcnt(0)" ::: "memory");   // gen-s prefetch done
    __builtin_amdgcn_sched_barrier(0);
    if (s + 1 < 128)
      pref_node(lane, topoS[s + 1], cur ^ 1, W1Pg, W2Pg, parlist, w1buf, w2buf, plbuf);

    // in-step small loads (consumed hundreds of cycles later)
    float zval = z[((size_t)b * 128 + node) * 64 + lane];
    float b1v = b1[node * 32 + (lane & 31)];
    float b2v = b2[node * 64 + lane];

    // --- parent aggregation (padded-to-16 index list; idx 128 -> zero row) ---
    const int pc = ecS[node];
    const int* pl = plbuf[cur];
    float agg = 0.0f;
    for (int i = 0; i < pc; i += 16) {
      int4 p0 = *(const int4*)&pl[i];
      int4 p1 = *(const int4*)&pl[i + 4];
      int4 p2 = *(const int4*)&pl[i + 8];
      int4 p3 = *(const int4*)&pl[i + 12];
      agg += tz[p0.x * 64 + lane]; agg += tz[p0.y * 64 + lane];
      agg += tz[p0.z * 64 + lane]; agg += tz[p0.w * 64 + lane];
      agg += tz[p1.x * 64 + lane]; agg += tz[p1.y * 64 + lane];
      agg += tz[p1.z * 64 + lane]; agg += tz[p1.w * 64 + lane];
      agg += tz[p2.x * 64 + lane]; agg += tz[p2.y * 64 + lane];
      agg += tz[p2.z * 64 + lane]; agg += tz[p2.w * 64 + lane];
      agg += tz[p3.x * 64 + lane]; agg += tz[p3.y * 64 + lane];
      agg += tz[p3.z * 64 + lane]; agg += tz[p3.w * 64 + lane];
    }
    agg *= rcS[node];
    feat[lane] = zval;
    feat[64 + lane] = agg;
    __syncthreads();

    // --- GEMV1: hh = relu(W1 @ feat + b1); lane (j, half) does half the K ---
    const int j = lane & 31, half = lane >> 5;
    const uint32_t* w1 = w1buf[cur] + half * 1024;
    float a = 0.0f;
#pragma unroll
    for (int k2 = 0; k2 < 32; ++k2) {
      uint32_t w = w1[k2 * 32 + j];
      float2 f2 = *(const float2*)&feat[(half * 32 + k2) * 2];
      union { uint32_t u; float f; } lo, hi;
      lo.u = w << 16; hi.u = w & 0xffff0000u;
      a = fmaf(lo.f, f2.x, a);
      a = fmaf(hi.f, f2.y, a);
    }
    a += __shfl_xor(a, 32);
    float hh = fmaxf(a + b1v, 0.0f);
    if (lane < 32) hhs[lane] = hh;
    __syncthreads();

    // --- GEMV2: out = W2 @ hh + b2; lane computes out[lane] ---
    const uint32_t* w2 = w2buf[cur];
    float o = b2v;
#pragma unroll
    for (int j2 = 0; j2 < 16; ++j2) {
      uint32_t w = w2[j2 * 64 + lane];
      float2 h2 = *(const float2*)&hhs[j2 * 2];
      union { uint32_t u; float f; } lo, hi;
      lo.u = w << 16; hi.u = w & 0xffff0000u;
      o = fmaf(lo.f, h2.x, o);
      o = fmaf(hi.f, h2.y, o);
    }
    tz[node * 64 + lane] = o;
    ztb[((size_t)b * 128 + node) * 64 + lane] = f2b(o);
    __syncthreads();
  }
}

// ---------- launch ----------
extern "C" void kernel_launch(void* const* d_in, const int* in_sizes, int n_in,
                              void* d_out, int out_size, void* d_ws, size_t ws_size,
                              hipStream_t stream) {
  const float* x          = (const float*)d_in[0];
  const float* eps        = (const float*)d_in[1];
  const float* adj_logits = (const float*)d_in[2];
  const float* enc_W1     = (const float*)d_in[3];
  const float* enc_b1     = (const float*)d_in[4];
  const float* enc_W2     = (const float*)d_in[5];
  const float* enc_b2     = (const float*)d_in[6];
  const float* mu_W       = (const float*)d_in[7];
  const float* mu_b       = (const float*)d_in[8];
  const float* lv_W       = (const float*)d_in[9];
  const float* lv_b       = (const float*)d_in[10];
  const float* dec_W1     = (const float*)d_in[11];
  const float* dec_b1     = (const float*)d_in[12];
  const float* dec_W2     = (const float*)d_in[13];
  const float* dec_b2     = (const float*)d_in[14];
  const float* dec_W3     = (const float*)d_in[15];
  const float* dec_b3     = (const float*)d_in[16];
  const float* sem_W1     = (const float*)d_in[17];
  const float* sem_b1     = (const float*)d_in[18];
  const float* sem_W2     = (const float*)d_in[19];
  const float* sem_b2     = (const float*)d_in[20];
  const int*   topo       = (const int*)d_in[21];

  float* out      = (float*)d_out;
  float* out_recon = out;
  float* out_mu    = out + 33554432;
  float* out_lv    = out + 35651584;
  float* out_adj   = out + 37748736;
  float* out_kl    = out + 37765120;

  char* ws = (char*)d_ws;
  u16*   xb      = (u16*)(ws + 0);              // 67,108,864 B (x bf16)
  u16*   d2b     = (u16*)(ws + 0);              // alias: d2 after xb is dead
  u16*   h1b     = (u16*)(ws + 67108864);       // 33,554,432 B
  u16*   d1b     = h1b;                          // alias: d1 after h1 is dead
  u16*   h2b     = (u16*)(ws + 100663296);      // 16,777,216 B
  float* mulv    = (float*)(ws + 117440512);    // 16,777,216 B
  float* zbuf    = (float*)(ws + 134217728);    //  8,388,608 B
  u16*   ztb     = (u16*)(ws + 142606336);      //  4,194,304 B
  u16*   wb      = (u16*)(ws + 146800640);      //  2,719,744 B
  uint32_t* W1P  = (uint32_t*)(ws + 149520384); //  1,048,576 B
  uint32_t* W2P  = (uint32_t*)(ws + 150568960); //    524,288 B
  int*   parlist = (int*)(ws + 152666112);      //     65,536 B
  int*   ecnt    = (int*)(ws + 152731648);
  float* rcnt    = (float*)(ws + 152732160);
  float* mbias   = (float*)(ws + 152732672);
  float* klp     = (float*)(ws + 152733184);    //     32,768 B

  u16* wE1 = wb;             // (512,1024)
  u16* wE2 = wb + 524288;    // (256,512)
  u16* wML = wb + 655360;    // (128,256) = mu_W rows ++ lv_W rows
  u16* wD1 = wb + 688128;    // (256,64)
  u16* wD2 = wb + 704512;    // (512,256)
  u16* wD3 = wb + 835584;    // (1024,512)

  prep_adj<<<1, 128, 0, stream>>>(adj_logits, topo, out_adj, parlist, ecnt, rcnt, mu_b, lv_b, mbias);
  prep_semP<<<128, 256, 0, stream>>>(sem_W1, sem_W2, W1P, W2P);
  cvt_weights<<<512, 256, 0, stream>>>(enc_W1, enc_W2, mu_W, lv_W, dec_W1, dec_W2, dec_W3, wb);
  cvt_f32_bf16<<<4096, 256, 0, stream>>>(x, xb, 8388608);

  dim3 blk(256);
  gemm_bt<1, 1><<<dim3(4, 256), blk, 0, stream>>>(xb,  wE1, enc_b1, h1b,  32768, 512, 1024);
  gemm_bt<1, 1><<<dim3(2, 256), blk, 0, stream>>>(h1b, wE2, enc_b2, h2b,  32768, 256, 512);
  gemm_bt<0, 0><<<dim3(1, 256), blk, 0, stream>>>(h2b, wML, mbias,  mulv, 32768, 128, 256);

  reparam_kernel<<<8192, 256, 0, stream>>>(mulv, eps, out_mu, out_lv, zbuf, klp);
  kl_final<<<1, 256, 0, stream>>>(klp, out_kl);

  sem_scan<<<256, 64, 0, stream>>>(zbuf, ztb, W1P, W2P, sem_b1, sem_b2, parlist, ecnt, rcnt, topo);

  gemm_bt<1, 1><<<dim3(2, 256), blk, 0, stream>>>(ztb, wD1, dec_b1, d1b,      32768, 256, 64);
  gemm_bt<1, 1><<<dim3(4, 256), blk, 0, stream>>>(d1b, wD2, dec_b2, d2b,      32768, 512, 256);
  gemm_bt<0, 0><<<dim3(8, 256), blk, 0, stream>>>(d2b, wD3, dec_b3, out_recon, 32768, 1024, 512);
}

// Round 4
// 715.067 us; speedup vs baseline: 2.0679x; 1.1173x over previous
//
#include <hip/hip_runtime.h>
#include <cstdint>
#include <cstddef>

typedef unsigned short u16;
typedef __attribute__((ext_vector_type(8))) short short8;
typedef __attribute__((ext_vector_type(4))) float f32x4;

// ---------- helpers ----------
__device__ __forceinline__ u16 f2b(float f) {
  union { float f; uint32_t u; } v; v.f = f;
  uint32_t u = v.u;
  uint32_t r = (u + 0x7FFFu + ((u >> 16) & 1u)) >> 16;
  return (u16)r;
}

__device__ __forceinline__ void gload_lds16(const void* g, void* l) {
  __builtin_amdgcn_global_load_lds(
      (const __attribute__((address_space(1))) void*)g,
      (__attribute__((address_space(3))) void*)l, 16, 0, 0);
}
__device__ __forceinline__ void gload_lds4(const void* g, void* l) {
  __builtin_amdgcn_global_load_lds(
      (const __attribute__((address_space(1))) void*)g,
      (__attribute__((address_space(3))) void*)l, 4, 0, 0);
}

// ---------- prep kernels ----------
__global__ void prep_adj(const float* __restrict__ logits, const int* __restrict__ topo,
                         float* __restrict__ adj_out, int* __restrict__ parlist,
                         int* __restrict__ ecnt, float* __restrict__ rcnt,
                         const float* __restrict__ mu_b, const float* __restrict__ lv_b,
                         float* __restrict__ mbias) {
  __shared__ int pos[128];
  int i = threadIdx.x;                 // node id, block of 128
  pos[topo[i]] = i;
  __syncthreads();
  int mypos = pos[i];
  int c_all = 0, c_eff = 0;
  for (int j = 0; j < 128; ++j) {
    float v = (i != j && logits[i * 128 + j] > 0.0f) ? 1.0f : 0.0f;
    adj_out[i * 128 + j] = v;
    if (v != 0.0f) {
      c_all++;
      if (pos[j] < mypos) parlist[i * 128 + c_eff++] = j;  // only earlier-in-order parents
    }
  }
  while (c_eff & 15) parlist[i * 128 + c_eff++] = 128;     // pad to x16 with zero-row idx
  ecnt[i] = c_eff;                                          // padded count
  rcnt[i] = 1.0f / fmaxf((float)c_all, 1.0f);              // denominator uses FULL count
  mbias[i] = (i < 64) ? mu_b[i] : lv_b[i - 64];
}

// SEM weights transposed to k-major f32 + packed per-node bias array
__global__ void prep_semT(const float* __restrict__ W1, const float* __restrict__ W2,
                          const float* __restrict__ b1, const float* __restrict__ b2,
                          float* __restrict__ W1T, float* __restrict__ W2T,
                          float* __restrict__ biasP) {
  int node = blockIdx.x, t = threadIdx.x;     // 256 threads
  const float* w1 = W1 + node * 4096;          // (j=32, k=128)
  float* o1 = W1T + node * 4096;               // [k][j]
  for (int e = t; e < 4096; e += 256) { int j = e >> 7, k = e & 127; o1[k * 32 + j] = w1[e]; }
  const float* w2 = W2 + node * 2048;          // (l=64, k=32)
  float* o2 = W2T + node * 2048;               // [k][l]
  for (int e = t; e < 2048; e += 256) { int l = e >> 5, k = e & 31; o2[k * 64 + l] = w2[e]; }
  if (t < 128) {
    float v = 0.0f;
    if (t < 32) v = b1[node * 32 + t];
    else if (t < 96) v = b2[node * 64 + (t - 32)];
    biasP[node * 128 + t] = v;
  }
}

__global__ __launch_bounds__(256)
void cvt_weights(const float* __restrict__ e1, const float* __restrict__ e2,
                 const float* __restrict__ muw, const float* __restrict__ lvw,
                 const float* __restrict__ d1, const float* __restrict__ d2,
                 const float* __restrict__ d3, u16* __restrict__ dst) {
  int i = blockIdx.x * 256 + threadIdx.x;
  int stride = gridDim.x * 256;
  for (; i < 1359872; i += stride) {
    float v;
    if      (i < 524288) v = e1[i];
    else if (i < 655360) v = e2[i - 524288];
    else if (i < 671744) v = muw[i - 655360];
    else if (i < 688128) v = lvw[i - 671744];
    else if (i < 704512) v = d1[i - 688128];
    else if (i < 835584) v = d2[i - 704512];
    else                 v = d3[i - 835584];
    dst[i] = f2b(v);
  }
}

__global__ __launch_bounds__(256)
void cvt_f32_bf16(const float* __restrict__ src, u16* __restrict__ dst, size_t n4) {
  size_t i = (size_t)blockIdx.x * blockDim.x + threadIdx.x;
  size_t stride = (size_t)gridDim.x * blockDim.x;
  for (; i < n4; i += stride) {
    float4 v = ((const float4*)src)[i];
    ushort4 o;
    o.x = f2b(v.x); o.y = f2b(v.y); o.z = f2b(v.z); o.w = f2b(v.w);
    ((ushort4*)dst)[i] = o;
  }
}

// ---------- bf16 MFMA GEMM: C = act(A @ W^T + bias) ----------
// Flattened 1D grid with XCD-aware swizzle (T1): each XCD owns a contiguous
// 32-m-tile chunk, n iterating fastest -> A-panel reused from XCD L2.
// OUT_MODE: 0=f32 linear, 1=bf16 linear, 2=mu/lv split into d_out halves.
template <int OUT_MODE, int RELU>
__global__ __launch_bounds__(256)
void gemm_bt(const u16* __restrict__ A, const u16* __restrict__ W,
             const float* __restrict__ bias, void* __restrict__ Cout,
             int M, int Ncols, int K, int gx) {
  __shared__ __align__(16) u16 As[128 * 64];
  __shared__ __align__(16) u16 Bs[128 * 64];
  const int tid = threadIdx.x;
  const int bid = blockIdx.x;
  const int xcd = bid & 7, w = bid >> 3;
  const int gy8 = (int)(gridDim.x >> 3) / gx;   // = (M/128)/8
  const int tile_n = w % gx;
  const int tile_m = xcd * gy8 + w / gx;
  const int wid = tid >> 6, lane = tid & 63;
  const int wm = (wid >> 1) * 64, wn = (wid & 1) * 64;
  const int lr = lane & 15, lg = lane >> 4;
  f32x4 acc[4][4] = {};
  const size_t arow0 = (size_t)tile_m * 128;
  const size_t brow0 = (size_t)tile_n * 128;

  for (int kt = 0; kt < K; kt += 64) {
#pragma unroll
    for (int is = 0; is < 4; ++is) {
      int e = is * 2048 + tid * 8;   // element index in 128x64 tile
      int r = e >> 6, c = e & 63;
      gload_lds16(A + (arow0 + r) * K + kt + c, &As[e]);
      gload_lds16(W + (brow0 + r) * K + kt + c, &Bs[e]);
    }
    __syncthreads();
#pragma unroll
    for (int kk = 0; kk < 64; kk += 32) {
      short8 av[4], bv[4];
#pragma unroll
      for (int m = 0; m < 4; ++m)
        av[m] = *(const short8*)&As[(wm + m * 16 + lr) * 64 + kk + lg * 8];
#pragma unroll
      for (int n = 0; n < 4; ++n)
        bv[n] = *(const short8*)&Bs[(wn + n * 16 + lr) * 64 + kk + lg * 8];
#pragma unroll
      for (int m = 0; m < 4; ++m)
#pragma unroll
        for (int n = 0; n < 4; ++n)
          acc[m][n] = __builtin_amdgcn_mfma_f32_16x16x32_bf16(av[m], bv[n], acc[m][n], 0, 0, 0);
    }
    __syncthreads();
  }
  // epilogue: C/D layout col = lane&15, row = (lane>>4)*4 + reg  [m89-verified]
#pragma unroll
  for (int n = 0; n < 4; ++n) {
    int col = (int)brow0 + wn + n * 16 + lr;
    float bval = bias[col];
#pragma unroll
    for (int m = 0; m < 4; ++m) {
#pragma unroll
      for (int r = 0; r < 4; ++r) {
        int row = (int)arow0 + wm + m * 16 + lg * 4 + r;
        float v = acc[m][n][r] + bval;
        if (RELU) v = fmaxf(v, 0.0f);
        if (OUT_MODE == 1) ((u16*)Cout)[(size_t)row * Ncols + col] = f2b(v);
        else if (OUT_MODE == 0) ((float*)Cout)[(size_t)row * Ncols + col] = v;
        else {  // mu/lv split: Cout = out_mu, out_lv follows at +2097152 elements
          float* muo = (float*)Cout;
          float* lvo = muo + 2097152;
          if (col < 64) muo[(size_t)row * 64 + col] = v;
          else          lvo[(size_t)row * 64 + (col - 64)] = v;
        }
      }
    }
  }
}

// ---------- reparameterize + KL partials (mu/lv already in d_out) ----------
__global__ __launch_bounds__(256)
void reparam_kernel(const float* __restrict__ mo, const float* __restrict__ lo,
                    const float* __restrict__ eps,
                    float* __restrict__ z, float* __restrict__ klpart) {
  int gid = blockIdx.x * 256 + threadIdx.x;   // over B*N*L = 2,097,152
  float mu = mo[gid];
  float lv = lo[gid];
  float e = eps[gid];
  z[gid] = mu + e * expf(0.5f * lv);
  float kt = 1.0f + lv - mu * mu - expf(lv);
  for (int o = 32; o > 0; o >>= 1) kt += __shfl_down(kt, o);
  __shared__ float red[4];
  int lane = threadIdx.x & 63, w = threadIdx.x >> 6;
  if (lane == 0) red[w] = kt;
  __syncthreads();
  if (threadIdx.x == 0) klpart[blockIdx.x] = red[0] + red[1] + red[2] + red[3];
}

__global__ void kl_final(const float* __restrict__ klpart, float* __restrict__ out) {
  __shared__ float red[256];
  float s = 0.0f;
  for (int i = threadIdx.x; i < 8192; i += 256) s += klpart[i];
  red[threadIdx.x] = s;
  __syncthreads();
  for (int st = 128; st > 0; st >>= 1) {
    if (threadIdx.x < st) red[threadIdx.x] += red[threadIdx.x + st];
    __syncthreads();
  }
  if (threadIdx.x == 0) out[0] = -0.5f * red[0];
}

// ---------- SEM scan: 4 waves per batch element, f32 weights in LDS ----------
// Per step: [vmcnt(0); barrier] -> prefetch s+1 -> agg(4-way) -> GEMV1 (8-way K
// split + shfl + LDS reduce) -> GEMV2 (4-way) -> write tz/ztb. All operands
// (weights, parent list, z-row, biases) arrive via 1-step-ahead global_load_lds.
__device__ __forceinline__ void sem_pref(int wid, int lane, int nd, int bi, int b,
    const float* __restrict__ W1Tg, const float* __restrict__ W2Tg,
    const float* __restrict__ biasPg, const int* __restrict__ parlist,
    const float* __restrict__ z,
    float (*w1s)[4096], float (*w2s)[2048], int (*pls)[128],
    float (*zrs)[64], float (*bis)[128]) {
  // w1: 4096 f32, each wave stages 1024 f32 (4 x 16B/lane)
  const float* w1g = W1Tg + (size_t)nd * 4096 + wid * 1024 + lane * 4;
  float* w1d = &w1s[bi][wid * 1024 + lane * 4];
#pragma unroll
  for (int q = 0; q < 4; ++q) gload_lds16(w1g + q * 256, w1d + q * 256);
  if (wid >= 2) {            // w2: 2048 f32, waves 2/3 stage 1024 each
    int h = wid - 2;
    const float* w2g = W2Tg + (size_t)nd * 2048 + h * 1024 + lane * 4;
    float* w2d = &w2s[bi][h * 1024 + lane * 4];
#pragma unroll
    for (int q = 0; q < 4; ++q) gload_lds16(w2g + q * 256, w2d + q * 256);
  } else if (wid == 0) {     // parent list: 128 ints
    gload_lds4(parlist + nd * 128 + lane, &pls[bi][lane]);
    gload_lds4(parlist + nd * 128 + 64 + lane, &pls[bi][64 + lane]);
  } else {                   // wid == 1: z-row + biases
    gload_lds4(z + ((size_t)b * 128 + nd) * 64 + lane, &zrs[bi][lane]);
    gload_lds4(biasPg + nd * 128 + lane, &bis[bi][lane]);
    gload_lds4(biasPg + nd * 128 + 64 + lane, &bis[bi][64 + lane]);
  }
}

__global__ __launch_bounds__(256)
void sem_scan4(const float* __restrict__ z, u16* __restrict__ ztb,
               const float* __restrict__ W1Tg, const float* __restrict__ W2Tg,
               const float* __restrict__ biasPg,
               const int* __restrict__ parlist, const int* __restrict__ ecnt,
               const float* __restrict__ rcnt, const int* __restrict__ topo) {
  const int b = blockIdx.x, t = threadIdx.x;
  const int lane = t & 63, wid = t >> 6;
  __shared__ __align__(16) float tz[129 * 64];      // row 128 = zeros (pad target)
  __shared__ __align__(16) float w1s[2][4096];      // [k][j] f32, dbuf
  __shared__ __align__(16) float w2s[2][2048];      // [k][l] f32, dbuf
  __shared__ __align__(16) int   pls[2][128];
  __shared__ __align__(16) float zrs[2][64];
  __shared__ __align__(16) float bis[2][128];       // [0:32) b1, [32:96) b2
  __shared__ float feat[128];
  __shared__ float aggP[256];
  __shared__ float part1[128];
  __shared__ float part2[256];
  __shared__ float hhs[32];
  __shared__ int topoS[128];
  __shared__ int ecS[128];
  __shared__ float rcS[128];

  for (int i = t; i < 129 * 64; i += 256) tz[i] = 0.0f;
  if (t < 128) { topoS[t] = topo[t]; ecS[t] = ecnt[t]; rcS[t] = rcnt[t]; }
  __syncthreads();

  sem_pref(wid, lane, topoS[0], 0, b, W1Tg, W2Tg, biasPg, parlist, z,
           w1s, w2s, pls, zrs, bis);

  for (int s = 0; s < 128; ++s) {
    const int cur = s & 1;
    const int node = topoS[s];
    asm volatile("s_waitcnt vmcnt(0)" ::: "memory");   // own prefetch landed
    __syncthreads();                                    // all waves' prefetch + prev step done
    if (s + 1 < 128)
      sem_pref(wid, lane, topoS[s + 1], cur ^ 1, b, W1Tg, W2Tg, biasPg, parlist, z,
               w1s, w2s, pls, zrs, bis);

    // --- parent aggregation: wave g handles groups g*16, g*16+64, ... ---
    const int pc = ecS[node];
    const int* pl = pls[cur];
    float ap = 0.0f;
    for (int i = wid * 16; i < pc; i += 64) {
      int4 p0 = *(const int4*)&pl[i];
      int4 p1 = *(const int4*)&pl[i + 4];
      int4 p2 = *(const int4*)&pl[i + 8];
      int4 p3 = *(const int4*)&pl[i + 12];
      ap += tz[p0.x * 64 + lane]; ap += tz[p0.y * 64 + lane];
      ap += tz[p0.z * 64 + lane]; ap += tz[p0.w * 64 + lane];
      ap += tz[p1.x * 64 + lane]; ap += tz[p1.y * 64 + lane];
      ap += tz[p1.z * 64 + lane]; ap += tz[p1.w * 64 + lane];
      ap += tz[p2.x * 64 + lane]; ap += tz[p2.y * 64 + lane];
      ap += tz[p2.z * 64 + lane]; ap += tz[p2.w * 64 + lane];
      ap += tz[p3.x * 64 + lane]; ap += tz[p3.y * 64 + lane];
      ap += tz[p3.z * 64 + lane]; ap += tz[p3.w * 64 + lane];
    }
    aggP[wid * 64 + lane] = ap;
    __syncthreads();
    if (t < 64) {
      float agg = (aggP[t] + aggP[64 + t] + aggP[128 + t] + aggP[192 + t]) * rcS[node];
      feat[t] = zrs[cur][t];
      feat[64 + t] = agg;
    }
    __syncthreads();

    // --- GEMV1: 8-way K split; thread (j = t&31, sub = t>>5) sums 16 k ---
    {
      const int j = t & 31, sub = t >> 5;
      const float* w1 = &w1s[cur][sub * 512];
      float a = 0.0f;
#pragma unroll
      for (int kk = 0; kk < 16; ++kk)
        a = fmaf(w1[kk * 32 + j], feat[sub * 16 + kk], a);
      a += __shfl_xor(a, 32);                 // combine sub-pairs within wave
      if (lane < 32) part1[wid * 32 + j] = a; // one partial per wave per j
    }
    __syncthreads();
    if (t < 32) {
      float hv = part1[t] + part1[32 + t] + part1[64 + t] + part1[96 + t] + bis[cur][t];
      hhs[t] = fmaxf(hv, 0.0f);
    }
    __syncthreads();

    // --- GEMV2: 4-way K split; thread (l = lane, wave) sums 8 k ---
    {
      const float* w2 = &w2s[cur][wid * 512];
      float o = 0.0f;
#pragma unroll
      for (int kk = 0; kk < 8; ++kk)
        o = fmaf(w2[kk * 64 + lane], hhs[wid * 8 + kk], o);
      part2[wid * 64 + lane] = o;
    }
    __syncthreads();
    if (t < 64) {
      float ov = part2[t] + part2[64 + t] + part2[128 + t] + part2[192 + t] + bis[cur][32 + t];
      tz[node * 64 + t] = ov;
      ztb[((size_t)b * 128 + node) * 64 + t] = f2b(ov);
    }
    // next iteration's top barrier orders the tz write vs. the next agg reads
  }
}

// ---------- launch ----------
extern "C" void kernel_launch(void* const* d_in, const int* in_sizes, int n_in,
                              void* d_out, int out_size, void* d_ws, size_t ws_size,
                              hipStream_t stream) {
  const float* x          = (const float*)d_in[0];
  const float* eps        = (const float*)d_in[1];
  const float* adj_logits = (const float*)d_in[2];
  const float* enc_W1     = (const float*)d_in[3];
  const float* enc_b1     = (const float*)d_in[4];
  const float* enc_W2     = (const float*)d_in[5];
  const float* enc_b2     = (const float*)d_in[6];
  const float* mu_W       = (const float*)d_in[7];
  const float* mu_b       = (const float*)d_in[8];
  const float* lv_W       = (const float*)d_in[9];
  const float* lv_b       = (const float*)d_in[10];
  const float* dec_W1     = (const float*)d_in[11];
  const float* dec_b1     = (const float*)d_in[12];
  const float* dec_W2     = (const float*)d_in[13];
  const float* dec_b2     = (const float*)d_in[14];
  const float* dec_W3     = (const float*)d_in[15];
  const float* dec_b3     = (const float*)d_in[16];
  const float* sem_W1     = (const float*)d_in[17];
  const float* sem_b1     = (const float*)d_in[18];
  const float* sem_W2     = (const float*)d_in[19];
  const float* sem_b2     = (const float*)d_in[20];
  const int*   topo       = (const int*)d_in[21];

  float* out       = (float*)d_out;
  float* out_recon = out;
  float* out_mu    = out + 33554432;
  float* out_lv    = out + 35651584;
  float* out_adj   = out + 37748736;
  float* out_kl    = out + 37765120;

  char* ws = (char*)d_ws;
  u16*   xb      = (u16*)(ws + 0);              // 67,108,864 B (x bf16)
  u16*   d2b     = (u16*)(ws + 0);              // alias: d2 after xb is dead
  u16*   h1b     = (u16*)(ws + 67108864);       // 33,554,432 B
  u16*   d1b     = h1b;                          // alias: d1 after h1 is dead
  u16*   h2b     = (u16*)(ws + 100663296);      // 16,777,216 B
  float* zbuf    = (float*)(ws + 117440512);    //  8,388,608 B
  u16*   ztb     = (u16*)(ws + 125829120);      //  4,194,304 B
  u16*   wb      = (u16*)(ws + 130023424);      //  2,719,744 B
  float* W1T     = (float*)(ws + 132743168);    //  2,097,152 B
  float* W2T     = (float*)(ws + 134840320);    //  1,048,576 B
  float* biasP   = (float*)(ws + 135888896);    //     65,536 B
  int*   parlist = (int*)(ws + 135954432);      //     65,536 B
  int*   ecnt    = (int*)(ws + 136019968);      //        512 B
  float* rcnt    = (float*)(ws + 136020480);
  float* mbias   = (float*)(ws + 136020992);
  float* klp     = (float*)(ws + 136021504);    //     32,768 B  (ends ~136.05 MB)

  u16* wE1 = wb;             // (512,1024)
  u16* wE2 = wb + 524288;    // (256,512)
  u16* wML = wb + 655360;    // (128,256) = mu_W rows ++ lv_W rows
  u16* wD1 = wb + 688128;    // (256,64)
  u16* wD2 = wb + 704512;    // (512,256)
  u16* wD3 = wb + 835584;    // (1024,512)

  prep_adj<<<1, 128, 0, stream>>>(adj_logits, topo, out_adj, parlist, ecnt, rcnt, mu_b, lv_b, mbias);
  prep_semT<<<128, 256, 0, stream>>>(sem_W1, sem_W2, sem_b1, sem_b2, W1T, W2T, biasP);
  cvt_weights<<<512, 256, 0, stream>>>(enc_W1, enc_W2, mu_W, lv_W, dec_W1, dec_W2, dec_W3, wb);
  cvt_f32_bf16<<<4096, 256, 0, stream>>>(x, xb, 8388608);

  dim3 blk(256);
  gemm_bt<1, 1><<<dim3(4 * 256), blk, 0, stream>>>(xb,  wE1, enc_b1, h1b,    32768, 512, 1024, 4);
  gemm_bt<1, 1><<<dim3(2 * 256), blk, 0, stream>>>(h1b, wE2, enc_b2, h2b,    32768, 256, 512, 2);
  gemm_bt<2, 0><<<dim3(1 * 256), blk, 0, stream>>>(h2b, wML, mbias,  out_mu, 32768, 128, 256, 1);

  reparam_kernel<<<8192, 256, 0, stream>>>(out_mu, out_lv, eps, zbuf, klp);
  kl_final<<<1, 256, 0, stream>>>(klp, out_kl);

  sem_scan4<<<256, 256, 0, stream>>>(zbuf, ztb, W1T, W2T, biasP, parlist, ecnt, rcnt, topo);

  gemm_bt<1, 1><<<dim3(2 * 256), blk, 0, stream>>>(ztb, wD1, dec_b1, d1b,       32768, 256, 64, 2);
  gemm_bt<1, 1><<<dim3(4 * 256), blk, 0, stream>>>(d1b, wD2, dec_b2, d2b,       32768, 512, 256, 4);
  gemm_bt<0, 0><<<dim3(8 * 256), blk, 0, stream>>>(d2b, wD3, dec_b3, out_recon, 32768, 1024, 512, 8);
}

// Round 5
// 683.433 us; speedup vs baseline: 2.1636x; 1.0463x over previous
//
#include <hip/hip_runtime.h>
#include <cstdint>
#include <cstddef>

typedef unsigned short u16;
typedef __attribute__((ext_vector_type(8))) short short8;
typedef __attribute__((ext_vector_type(4))) float f32x4;

// ---------- helpers ----------
__device__ __forceinline__ u16 f2b(float f) {
  union { float f; uint32_t u; } v; v.f = f;
  uint32_t u = v.u;
  uint32_t r = (u + 0x7FFFu + ((u >> 16) & 1u)) >> 16;
  return (u16)r;
}

__device__ __forceinline__ void gload_lds16(const void* g, void* l) {
  __builtin_amdgcn_global_load_lds(
      (const __attribute__((address_space(1))) void*)g,
      (__attribute__((address_space(3))) void*)l, 16, 0, 0);
}
__device__ __forceinline__ void gload_lds4(const void* g, void* l) {
  __builtin_amdgcn_global_load_lds(
      (const __attribute__((address_space(1))) void*)g,
      (__attribute__((address_space(3))) void*)l, 4, 0, 0);
}

// ---------- prep kernels ----------
// One wave per adjacency row: ballot/popcount prefix builds ordered parent list.
__global__ __launch_bounds__(64)
void prep_adj(const float* __restrict__ logits, const int* __restrict__ topo,
              float* __restrict__ adj_out, int* __restrict__ parlist,
              int* __restrict__ ecnt, float* __restrict__ rcnt,
              const float* __restrict__ mu_b, const float* __restrict__ lv_b,
              float* __restrict__ mbias) {
  __shared__ int pos_s[128];
  const int i = blockIdx.x, lane = threadIdx.x;
  pos_s[topo[lane]] = lane;
  pos_s[topo[64 + lane]] = 64 + lane;
  __syncthreads();
  const int myp = pos_s[i];
  bool edge0 = (i != lane) && (logits[i * 128 + lane] > 0.0f);
  bool edge1 = (i != 64 + lane) && (logits[i * 128 + 64 + lane] > 0.0f);
  adj_out[i * 128 + lane] = edge0 ? 1.0f : 0.0f;
  adj_out[i * 128 + 64 + lane] = edge1 ? 1.0f : 0.0f;
  bool par0 = edge0 && (pos_s[lane] < myp);
  bool par1 = edge1 && (pos_s[64 + lane] < myp);
  uint64_t m0 = __ballot(par0);
  uint64_t m1 = __ballot(par1);
  uint64_t below = (lane == 0) ? 0ull : ((~0ull) >> (64 - lane));
  int c0 = __popcll(m0);
  int c_eff = c0 + __popcll(m1);
  if (par0) parlist[i * 128 + __popcll(m0 & below)] = lane;
  if (par1) parlist[i * 128 + c0 + __popcll(m1 & below)] = 64 + lane;
  int padded = (c_eff + 15) & ~15;
  if (lane < padded - c_eff) parlist[i * 128 + c_eff + lane] = 128;  // zero-row idx
  int c_all = __popcll(__ballot(edge0)) + __popcll(__ballot(edge1));
  if (lane == 0) {
    ecnt[i] = padded;
    rcnt[i] = 1.0f / fmaxf((float)c_all, 1.0f);      // denominator uses FULL count
    mbias[i] = (i < 64) ? mu_b[i] : lv_b[i - 64];
  }
}

// SEM weights: W1 bank-swizzled k-major f32, W2 plain k-major f32, packed bias
__global__ void prep_semS(const float* __restrict__ W1, const float* __restrict__ W2,
                          const float* __restrict__ b1, const float* __restrict__ b2,
                          float* __restrict__ W1S, float* __restrict__ W2T,
                          float* __restrict__ biasP) {
  int node = blockIdx.x, t = threadIdx.x;      // 256 threads
  const float* w1 = W1 + node * 4096;          // (j=32, k=128) row-major
  float* o1 = W1S + node * 4096;               // [k][j ^ ((k&7)<<2)]
  for (int d = t; d < 4096; d += 256) {
    int k = d >> 5, jx = d & 31, j = jx ^ ((k & 7) << 2);
    o1[d] = w1[j * 128 + k];
  }
  const float* w2 = W2 + node * 2048;          // (l=64, k=32) row-major
  float* o2 = W2T + node * 2048;               // [k][l]
  for (int d = t; d < 2048; d += 256) {
    int k = d >> 6, l = d & 63;
    o2[d] = w2[l * 32 + k];
  }
  if (t < 128) {
    float v = 0.0f;
    if (t < 32) v = b1[node * 32 + t];
    else if (t < 96) v = b2[node * 64 + (t - 32)];
    biasP[node * 128 + t] = v;
  }
}

__global__ __launch_bounds__(256)
void cvt_weights(const float* __restrict__ e1, const float* __restrict__ e2,
                 const float* __restrict__ muw, const float* __restrict__ lvw,
                 const float* __restrict__ d1, const float* __restrict__ d2,
                 const float* __restrict__ d3, u16* __restrict__ dst) {
  int i = blockIdx.x * 256 + threadIdx.x;
  int stride = gridDim.x * 256;
  for (; i < 1359872; i += stride) {
    float v;
    if      (i < 524288) v = e1[i];
    else if (i < 655360) v = e2[i - 524288];
    else if (i < 671744) v = muw[i - 655360];
    else if (i < 688128) v = lvw[i - 671744];
    else if (i < 704512) v = d1[i - 688128];
    else if (i < 835584) v = d2[i - 704512];
    else                 v = d3[i - 835584];
    dst[i] = f2b(v);
  }
}

__global__ __launch_bounds__(256)
void cvt_f32_bf16(const float* __restrict__ src, u16* __restrict__ dst, size_t n4) {
  size_t i = (size_t)blockIdx.x * blockDim.x + threadIdx.x;
  size_t stride = (size_t)gridDim.x * blockDim.x;
  for (; i < n4; i += stride) {
    float4 v = ((const float4*)src)[i];
    ushort4 o;
    o.x = f2b(v.x); o.y = f2b(v.y); o.z = f2b(v.z); o.w = f2b(v.w);
    ((ushort4*)dst)[i] = o;
  }
}

// ---------- bf16 MFMA GEMM: C = act(A @ W^T + bias) ----------
// Flattened 1D grid, XCD-aware swizzle. OUT_MODE: 0=f32, 1=bf16, 2=mu/lv split.
template <int OUT_MODE, int RELU>
__global__ __launch_bounds__(256)
void gemm_bt(const u16* __restrict__ A, const u16* __restrict__ W,
             const float* __restrict__ bias, void* __restrict__ Cout,
             int M, int Ncols, int K, int gx) {
  __shared__ __align__(16) u16 As[128 * 64];
  __shared__ __align__(16) u16 Bs[128 * 64];
  const int tid = threadIdx.x;
  const int bid = blockIdx.x;
  const int xcd = bid & 7, w = bid >> 3;
  const int gy8 = (int)(gridDim.x >> 3) / gx;   // = (M/128)/8
  const int tile_n = w % gx;
  const int tile_m = xcd * gy8 + w / gx;
  const int wid = tid >> 6, lane = tid & 63;
  const int wm = (wid >> 1) * 64, wn = (wid & 1) * 64;
  const int lr = lane & 15, lg = lane >> 4;
  f32x4 acc[4][4] = {};
  const size_t arow0 = (size_t)tile_m * 128;
  const size_t brow0 = (size_t)tile_n * 128;

  for (int kt = 0; kt < K; kt += 64) {
#pragma unroll
    for (int is = 0; is < 4; ++is) {
      int e = is * 2048 + tid * 8;   // element index in 128x64 tile
      int r = e >> 6, c = e & 63;
      gload_lds16(A + (arow0 + r) * K + kt + c, &As[e]);
      gload_lds16(W + (brow0 + r) * K + kt + c, &Bs[e]);
    }
    __syncthreads();
#pragma unroll
    for (int kk = 0; kk < 64; kk += 32) {
      short8 av[4], bv[4];
#pragma unroll
      for (int m = 0; m < 4; ++m)
        av[m] = *(const short8*)&As[(wm + m * 16 + lr) * 64 + kk + lg * 8];
#pragma unroll
      for (int n = 0; n < 4; ++n)
        bv[n] = *(const short8*)&Bs[(wn + n * 16 + lr) * 64 + kk + lg * 8];
#pragma unroll
      for (int m = 0; m < 4; ++m)
#pragma unroll
        for (int n = 0; n < 4; ++n)
          acc[m][n] = __builtin_amdgcn_mfma_f32_16x16x32_bf16(av[m], bv[n], acc[m][n], 0, 0, 0);
    }
    __syncthreads();
  }
  // epilogue: C/D layout col = lane&15, row = (lane>>4)*4 + reg  [m89-verified]
#pragma unroll
  for (int n = 0; n < 4; ++n) {
    int col = (int)brow0 + wn + n * 16 + lr;
    float bval = bias[col];
#pragma unroll
    for (int m = 0; m < 4; ++m) {
#pragma unroll
      for (int r = 0; r < 4; ++r) {
        int row = (int)arow0 + wm + m * 16 + lg * 4 + r;
        float v = acc[m][n][r] + bval;
        if (RELU) v = fmaxf(v, 0.0f);
        if (OUT_MODE == 1) ((u16*)Cout)[(size_t)row * Ncols + col] = f2b(v);
        else if (OUT_MODE == 0) ((float*)Cout)[(size_t)row * Ncols + col] = v;
        else {  // mu/lv split: Cout = out_mu, out_lv follows at +2097152 elements
          float* muo = (float*)Cout;
          float* lvo = muo + 2097152;
          if (col < 64) muo[(size_t)row * 64 + col] = v;
          else          lvo[(size_t)row * 64 + (col - 64)] = v;
        }
      }
    }
  }
}

// ---------- reparameterize (x4 vectorized) + KL partials ----------
__global__ __launch_bounds__(256)
void reparam_kernel(const float* __restrict__ mo, const float* __restrict__ lo,
                    const float* __restrict__ eps,
                    float* __restrict__ z, float* __restrict__ klpart) {
  int gid = blockIdx.x * 256 + threadIdx.x;   // 2048 blocks x 256 thr x 4 elems
  float4 mu4 = ((const float4*)mo)[gid];
  float4 lv4 = ((const float4*)lo)[gid];
  float4 e4  = ((const float4*)eps)[gid];
  float4 z4;
  z4.x = mu4.x + e4.x * expf(0.5f * lv4.x);
  z4.y = mu4.y + e4.y * expf(0.5f * lv4.y);
  z4.z = mu4.z + e4.z * expf(0.5f * lv4.z);
  z4.w = mu4.w + e4.w * expf(0.5f * lv4.w);
  ((float4*)z)[gid] = z4;
  float kt = 4.0f + lv4.x + lv4.y + lv4.z + lv4.w
           - mu4.x * mu4.x - mu4.y * mu4.y - mu4.z * mu4.z - mu4.w * mu4.w
           - expf(lv4.x) - expf(lv4.y) - expf(lv4.z) - expf(lv4.w);
  for (int o = 32; o > 0; o >>= 1) kt += __shfl_down(kt, o);
  __shared__ float red[4];
  int lane = threadIdx.x & 63, w = threadIdx.x >> 6;
  if (lane == 0) red[w] = kt;
  __syncthreads();
  if (threadIdx.x == 0) klpart[blockIdx.x] = red[0] + red[1] + red[2] + red[3];
}

__global__ void kl_final(const float* __restrict__ klpart, float* __restrict__ out) {
  __shared__ float red[256];
  float s = 0.0f;
  for (int i = threadIdx.x; i < 2048; i += 256) s += klpart[i];
  red[threadIdx.x] = s;
  __syncthreads();
  for (int st = 128; st > 0; st >>= 1) {
    if (threadIdx.x < st) red[threadIdx.x] += red[threadIdx.x + st];
    __syncthreads();
  }
  if (threadIdx.x == 0) out[0] = -0.5f * red[0];
}

// ---------- SEM scan: 4 waves/batch elem, 4 barriers/step, shfl reduces ----------
__device__ __forceinline__ void sem_pref(int wid, int lane, int nd, int bi, int b,
    const float* __restrict__ W1Sg, const float* __restrict__ W2Tg,
    const float* __restrict__ biasPg, const int* __restrict__ parlist,
    const float* __restrict__ z,
    float (*w1s)[4096], float (*w2s)[2048], int (*pls)[128],
    float (*zrs)[64], float (*bis)[128]) {
  // w1: 4096 f32; each wave stages 1024 f32 (4 x 1KB issues)
  const float* w1g = W1Sg + (size_t)nd * 4096 + wid * 1024 + lane * 4;
  float* w1d = &w1s[bi][wid * 1024 + lane * 4];
#pragma unroll
  for (int q = 0; q < 4; ++q) gload_lds16(w1g + q * 256, w1d + q * 256);
  if (wid >= 2) {            // w2: 2048 f32; waves 2/3 stage 1024 each
    int h = wid - 2;
    const float* w2g = W2Tg + (size_t)nd * 2048 + h * 1024 + lane * 4;
    float* w2d = &w2s[bi][h * 1024 + lane * 4];
#pragma unroll
    for (int q = 0; q < 4; ++q) gload_lds16(w2g + q * 256, w2d + q * 256);
  } else if (wid == 0) {     // parent list: 128 ints
    gload_lds4(parlist + nd * 128 + lane, &pls[bi][lane]);
    gload_lds4(parlist + nd * 128 + 64 + lane, &pls[bi][64 + lane]);
  } else {                   // wid == 1: z-row + biases
    gload_lds4(z + ((size_t)b * 128 + nd) * 64 + lane, &zrs[bi][lane]);
    gload_lds4(biasPg + nd * 128 + lane, &bis[bi][lane]);
    gload_lds4(biasPg + nd * 128 + 64 + lane, &bis[bi][64 + lane]);
  }
}

__global__ __launch_bounds__(256)
void sem_scan4(const float* __restrict__ z, u16* __restrict__ ztb,
               const float* __restrict__ W1Sg, const float* __restrict__ W2Tg,
               const float* __restrict__ biasPg,
               const int* __restrict__ parlist, const int* __restrict__ ecnt,
               const float* __restrict__ rcnt, const int* __restrict__ topo) {
  const int b = blockIdx.x, t = threadIdx.x;
  const int lane = t & 63, wid = t >> 6;
  __shared__ __align__(16) float tz[129 * 64];      // row 128 = zeros (pad target)
  __shared__ __align__(16) float w1s[2][4096];      // swizzled [k][j^((k&7)<<2)]
  __shared__ __align__(16) float w2s[2][2048];      // [k][l]
  __shared__ __align__(16) int   pls[2][128];
  __shared__ __align__(16) float zrs[2][64];
  __shared__ __align__(16) float bis[2][128];       // [0:32) b1, [32:96) b2
  __shared__ float feat[128];
  __shared__ float aggP[256];
  __shared__ float hhs[32];
  __shared__ int topoS[128];
  __shared__ int ecS[128];
  __shared__ float rcS[128];

  for (int i = t; i < 129 * 64; i += 256) tz[i] = 0.0f;
  if (t < 128) { topoS[t] = topo[t]; ecS[t] = ecnt[t]; rcS[t] = rcnt[t]; }
  __syncthreads();

  sem_pref(wid, lane, topoS[0], 0, b, W1Sg, W2Tg, biasPg, parlist, z,
           w1s, w2s, pls, zrs, bis);

  for (int s = 0; s < 128; ++s) {
    const int cur = s & 1;
    const int node = topoS[s];
    // waves 0-1 carry one trailing ztb store from step s-1: allow it in flight
    if (s > 0 && wid < 2) asm volatile("s_waitcnt vmcnt(1)" ::: "memory");
    else                  asm volatile("s_waitcnt vmcnt(0)" ::: "memory");
    __builtin_amdgcn_sched_barrier(0);
    __syncthreads();                                   // B1: prefetch + prev tz visible
    if (s + 1 < 128)
      sem_pref(wid, lane, topoS[s + 1], cur ^ 1, b, W1Sg, W2Tg, biasPg, parlist, z,
               w1s, w2s, pls, zrs, bis);

    // --- parent aggregation: wave g handles index groups g*16, g*16+64 ---
    const int pc = ecS[node];
    const int* pl = pls[cur];
    float ap = 0.0f;
    for (int i = wid * 16; i < pc; i += 64) {
      int4 p0 = *(const int4*)&pl[i];
      int4 p1 = *(const int4*)&pl[i + 4];
      int4 p2 = *(const int4*)&pl[i + 8];
      int4 p3 = *(const int4*)&pl[i + 12];
      ap += tz[p0.x * 64 + lane]; ap += tz[p0.y * 64 + lane];
      ap += tz[p0.z * 64 + lane]; ap += tz[p0.w * 64 + lane];
      ap += tz[p1.x * 64 + lane]; ap += tz[p1.y * 64 + lane];
      ap += tz[p1.z * 64 + lane]; ap += tz[p1.w * 64 + lane];
      ap += tz[p2.x * 64 + lane]; ap += tz[p2.y * 64 + lane];
      ap += tz[p2.z * 64 + lane]; ap += tz[p2.w * 64 + lane];
      ap += tz[p3.x * 64 + lane]; ap += tz[p3.y * 64 + lane];
      ap += tz[p3.z * 64 + lane]; ap += tz[p3.w * 64 + lane];
    }
    aggP[wid * 64 + lane] = ap;
    __syncthreads();                                   // B2
    if (t < 64) {
      feat[t] = zrs[cur][t];
      feat[64 + t] = (aggP[t] + aggP[64 + t] + aggP[128 + t] + aggP[192 + t]) * rcS[node];
    }
    __syncthreads();                                   // B3
    // --- GEMV1: j = wid*8 + (lane>>3), sub = lane&7 sums k = sub+8i ---
    {
      const int sub = lane & 7, j = wid * 8 + (lane >> 3);
      const float* w1 = w1s[cur];
      const int jx = j ^ (sub << 2);
      float a = 0.0f;
#pragma unroll
      for (int i = 0; i < 16; ++i) {
        int k = sub + 8 * i;
        a = fmaf(w1[k * 32 + jx], feat[k], a);
      }
      a += __shfl_xor(a, 1);
      a += __shfl_xor(a, 2);
      a += __shfl_xor(a, 4);
      if (sub == 0) hhs[j] = fmaxf(a + bis[cur][j], 0.0f);
    }
    __syncthreads();                                   // B4
    // --- GEMV2: waves 0-1; l = t>>1, ss = t&1 sums k = ss+2i ---
    if (t < 128) {
      const int ss = t & 1, l = t >> 1;
      const float* w2 = w2s[cur];
      float o = 0.0f;
#pragma unroll
      for (int i = 0; i < 16; ++i) {
        int k = ss + 2 * i;
        o = fmaf(w2[k * 64 + l], hhs[k], o);
      }
      o += __shfl_xor(o, 1);
      if (ss == 0) {
        float ov = o + bis[cur][32 + l];
        tz[node * 64 + l] = ov;
        ztb[((size_t)b * 128 + node) * 64 + l] = f2b(ov);
      }
    }
    // next step's B1 orders tz writes vs agg reads
  }
}

// ---------- launch ----------
extern "C" void kernel_launch(void* const* d_in, const int* in_sizes, int n_in,
                              void* d_out, int out_size, void* d_ws, size_t ws_size,
                              hipStream_t stream) {
  const float* x          = (const float*)d_in[0];
  const float* eps        = (const float*)d_in[1];
  const float* adj_logits = (const float*)d_in[2];
  const float* enc_W1     = (const float*)d_in[3];
  const float* enc_b1     = (const float*)d_in[4];
  const float* enc_W2     = (const float*)d_in[5];
  const float* enc_b2     = (const float*)d_in[6];
  const float* mu_W       = (const float*)d_in[7];
  const float* mu_b       = (const float*)d_in[8];
  const float* lv_W       = (const float*)d_in[9];
  const float* lv_b       = (const float*)d_in[10];
  const float* dec_W1     = (const float*)d_in[11];
  const float* dec_b1     = (const float*)d_in[12];
  const float* dec_W2     = (const float*)d_in[13];
  const float* dec_b2     = (const float*)d_in[14];
  const float* dec_W3     = (const float*)d_in[15];
  const float* dec_b3     = (const float*)d_in[16];
  const float* sem_W1     = (const float*)d_in[17];
  const float* sem_b1     = (const float*)d_in[18];
  const float* sem_W2     = (const float*)d_in[19];
  const float* sem_b2     = (const float*)d_in[20];
  const int*   topo       = (const int*)d_in[21];

  float* out       = (float*)d_out;
  float* out_recon = out;
  float* out_mu    = out + 33554432;
  float* out_lv    = out + 35651584;
  float* out_adj   = out + 37748736;
  float* out_kl    = out + 37765120;

  char* ws = (char*)d_ws;
  u16*   xb      = (u16*)(ws + 0);              // 67,108,864 B (x bf16)
  u16*   d2b     = (u16*)(ws + 0);              // alias: d2 after xb is dead
  u16*   h1b     = (u16*)(ws + 67108864);       // 33,554,432 B
  u16*   d1b     = h1b;                          // alias: d1 after h1 is dead
  u16*   h2b     = (u16*)(ws + 100663296);      // 16,777,216 B
  float* zbuf    = (float*)(ws + 117440512);    //  8,388,608 B
  u16*   ztb     = (u16*)(ws + 125829120);      //  4,194,304 B
  u16*   wb      = (u16*)(ws + 130023424);      //  2,719,744 B
  float* W1S     = (float*)(ws + 132743168);    //  2,097,152 B
  float* W2T     = (float*)(ws + 134840320);    //  1,048,576 B
  float* biasP   = (float*)(ws + 135888896);    //     65,536 B
  int*   parlist = (int*)(ws + 135954432);      //     65,536 B
  int*   ecnt    = (int*)(ws + 136019968);      //        512 B
  float* rcnt    = (float*)(ws + 136020480);
  float* mbias   = (float*)(ws + 136020992);
  float* klp     = (float*)(ws + 136021504);    //      8,192 B

  u16* wE1 = wb;             // (512,1024)
  u16* wE2 = wb + 524288;    // (256,512)
  u16* wML = wb + 655360;    // (128,256) = mu_W rows ++ lv_W rows
  u16* wD1 = wb + 688128;    // (256,64)
  u16* wD2 = wb + 704512;    // (512,256)
  u16* wD3 = wb + 835584;    // (1024,512)

  prep_adj<<<128, 64, 0, stream>>>(adj_logits, topo, out_adj, parlist, ecnt, rcnt, mu_b, lv_b, mbias);
  prep_semS<<<128, 256, 0, stream>>>(sem_W1, sem_W2, sem_b1, sem_b2, W1S, W2T, biasP);
  cvt_weights<<<512, 256, 0, stream>>>(enc_W1, enc_W2, mu_W, lv_W, dec_W1, dec_W2, dec_W3, wb);
  cvt_f32_bf16<<<4096, 256, 0, stream>>>(x, xb, 8388608);

  dim3 blk(256);
  gemm_bt<1, 1><<<dim3(4 * 256), blk, 0, stream>>>(xb,  wE1, enc_b1, h1b,    32768, 512, 1024, 4);
  gemm_bt<1, 1><<<dim3(2 * 256), blk, 0, stream>>>(h1b, wE2, enc_b2, h2b,    32768, 256, 512, 2);
  gemm_bt<2, 0><<<dim3(1 * 256), blk, 0, stream>>>(h2b, wML, mbias,  out_mu, 32768, 128, 256, 1);

  reparam_kernel<<<2048, 256, 0, stream>>>(out_mu, out_lv, eps, zbuf, klp);
  kl_final<<<1, 256, 0, stream>>>(klp, out_kl);

  sem_scan4<<<256, 256, 0, stream>>>(zbuf, ztb, W1S, W2T, biasP, parlist, ecnt, rcnt, topo);

  gemm_bt<1, 1><<<dim3(2 * 256), blk, 0, stream>>>(ztb, wD1, dec_b1, d1b,       32768, 256, 64, 2);
  gemm_bt<1, 1><<<dim3(4 * 256), blk, 0, stream>>>(d1b, wD2, dec_b2, d2b,       32768, 512, 256, 4);
  gemm_bt<0, 0><<<dim3(8 * 256), blk, 0, stream>>>(d2b, wD3, dec_b3, out_recon, 32768, 1024, 512, 8);
}